// Round 13
// baseline (21.954 us; speedup 1.0000x reference)
//
#include <hip/hip_runtime.h>

#define BN_EPS 1e-5f
#define MAGIC  0x5F3C9A17

// Dependency cone of the single consumed output position (center voxel):
//   out(8,8,8) <- x2[15..17]^3 (64ch) <- x1[29..35]^3 (32ch) <- voxel[28..36]^3
// All interior; no padding logic.
//
// SINGLE graph node, fence-free relaxed-AGENT-atomic handoff, ONE exchange.
// R12 lesson: 1-node with two exchange rounds == 2-node R6 (21.5us) -> the
// second exchange round replaced the dispatch slot. This round deletes
// exchange-2: g==0 per batch centralizes x3-reduce + FC (512 threads make
// the centralized finisher 2x wider than R10's slow 256-thr version);
// the other 15 blocks exit after publishing conv3 partials.
//
// Block (b = blk&15, g = blk>>4 in 0..15):
//   conv1 (all 32 ch, replicated)             -> s_x1 [343][32]
//   conv2 (4 co = g*4..): wave = (co_l, row-half), 32-ci butterfly
//        + cross-wave-half combine in LDS     -> s_x2f [4ci*27]
//   conv3-PARTIAL (4 ci x 128 co3)            -> part[b*16+g][128]; flag1
//   g!=0: exit.  g==0: poll 16 flag1, gather 2048 partials to LDS,
//   fixed-order reduce + BN + ReLU -> s_x3[128]; FC split-K (2 halves x
//   256 f, wp coalesced); out[b][f] = bp[f] + fcA[f] + fcB[f].
//
// Replay-safe: stale MAGIC -> finisher reads prior-replay partials, which
// are bitwise-identical (benign); post-poison flags=0xAAAAAAAA != MAGIC ->
// real wait. All determinism preserved (fixed-order sums, plain out write).
// R4/R5: VGPR pinning -> keep register demand moderate. R7: no coop launch.
// R9/R10: no __threadfence; relaxed AGENT atomics only.
__global__ __launch_bounds__(512, 2) void backbone_onenode_kernel(
    const float* __restrict__ voxel, const float* __restrict__ w1,
    const float* __restrict__ g1, const float* __restrict__ b1,
    const float* __restrict__ m1, const float* __restrict__ v1,
    const float* __restrict__ w2, const float* __restrict__ g2,
    const float* __restrict__ b2, const float* __restrict__ m2,
    const float* __restrict__ v2, const float* __restrict__ w3,
    const float* __restrict__ g3, const float* __restrict__ b3,
    const float* __restrict__ m3, const float* __restrict__ v3,
    const float* __restrict__ wp, const float* __restrict__ bp,
    float* __restrict__ part, int* __restrict__ flag1,
    float* __restrict__ out)
{
    const int b   = blockIdx.x & 15;    // g-major: blk = g*16 + b
    const int g   = blockIdx.x >> 4;    // 0..15
    const int tid = threadIdx.x;        // 0..511

    __shared__ float s_in[729];                  // 9^3 input patch
    __shared__ float s_w1[864];                  // 32 x 27
    __shared__ __align__(16) float s_x1[10976];  // [343 pos][32 ci]
    __shared__ __align__(16) float s_w2[3456];   // [4 co][32 ci][27]
    __shared__ float s_part2[216];               // conv2 wave-half partials [8][27]
    __shared__ float s_x2f[108];                 // conv2 out [4 ci][27]
    __shared__ float s_p[2048];                  // finisher: [16 gg][128 co3]
    __shared__ float s_x3[128];                  // BN+ReLU'd x3
    __shared__ float s_fc[512];                  // FC split-K partials [2][256]
    __shared__ float sa1[32], ss1[32], sa2[4], ss2[4];

    // ---- Phase 0: stage input patch + weights + folded BN consts ----
    const float* vb = voxel + (size_t)b * 262144;
    for (int i = tid; i < 729; i += 512) {
        int z = i / 81, r = i % 81, y = r / 9, x = r % 9;
        s_in[i] = vb[(28 + z) * 4096 + (28 + y) * 64 + (28 + x)];
    }
    for (int i = tid; i < 864; i += 512) s_w1[i] = w1[i];
    {   // w2 slice for this group's 4 co, coalesced float4
        const float4* src = (const float4*)(w2 + (size_t)g * 3456);
        float4* dst = (float4*)s_w2;
        for (int i = tid; i < 864; i += 512) dst[i] = src[i];
    }
    if (tid < 32) {
        float a = g1[tid] * rsqrtf(v1[tid] + BN_EPS);
        sa1[tid] = a; ss1[tid] = b1[tid] - m1[tid] * a;
    } else if (tid < 36) {
        int c = g * 4 + (tid - 32);
        float a = g2[c] * rsqrtf(v2[c] + BN_EPS);
        sa2[tid - 32] = a; ss2[tid - 32] = b2[c] - m2[c] * a;
    }
    __syncthreads();

    // ---- conv1 (stride 1) + BN + ReLU -> s_x1[pos][co] ----
    // Thread = (co = tid&31, rg = tid>>5 in 0..15); rows r = rg, rg+16.
    // s_in reads: 2 distinct addrs/wave (2 rows) -> 2-way broadcast, free.
    {
        const int co = tid & 31, rg = tid >> 5;
        float wc[27];
        #pragma unroll
        for (int k = 0; k < 27; ++k) wc[k] = s_w1[co * 27 + k];
        const float a = sa1[co], sh = ss1[co];
        for (int r = rg; r < 49; r += 16) {       // r = z*7 + y
            const int z = r / 7, y = r % 7;
            float acc[7];
            #pragma unroll
            for (int x = 0; x < 7; ++x) acc[x] = 0.f;
            #pragma unroll
            for (int kd = 0; kd < 3; ++kd)
            #pragma unroll
            for (int kh = 0; kh < 3; ++kh) {
                float row[9];
                #pragma unroll
                for (int x = 0; x < 9; ++x)
                    row[x] = s_in[(z + kd) * 81 + (y + kh) * 9 + x];
                #pragma unroll
                for (int kw = 0; kw < 3; ++kw) {
                    const float w = wc[kd * 9 + kh * 3 + kw];
                    #pragma unroll
                    for (int x = 0; x < 7; ++x)
                        acc[x] += row[x + kw] * w;
                }
            }
            #pragma unroll
            for (int x = 0; x < 7; ++x)
                s_x1[(r * 7 + x) * 32 + co] = fmaxf(acc[x] * a + sh, 0.f);
        }
    }
    __syncthreads();

    // ---- conv2 (stride 2): wave = (co_l = w>>1, rh = w&1) ----
    // rh splits the 49 (z,y) rows 25/24 at WAVE granularity (uniform branch
    // -> other half's code skipped via execz; reads/wave truly halve).
    // After full unroll, z/y/kd/kh fold to constants; p[] indices are
    // unroll-constants (no scratch).
    {
        const int w    = tid >> 6;       // wave 0..7
        const int co_l = w >> 1;         // 0..3 local output channel
        const int rh   = w & 1;          // row half
        const int ci   = tid & 31;       // input channel (lanes 32-63 mirror)

        float wr[27];
        const float* wl = s_w2 + (co_l * 32 + ci) * 27;
        #pragma unroll
        for (int k = 0; k < 27; ++k) wr[k] = wl[k];
        float p[27];
        #pragma unroll
        for (int q = 0; q < 27; ++q) p[q] = 0.f;

#define C2_BODY(zy)                                                          \
        {                                                                    \
            const int z_ = (zy) / 7, y_ = (zy) % 7;                          \
            float row[7];                                                    \
            _Pragma("unroll")                                                \
            for (int x = 0; x < 7; ++x)                                      \
                row[x] = s_x1[((zy) * 7 + x) * 32 + ci];                     \
            _Pragma("unroll")                                                \
            for (int i = 0; i < 3; ++i) {                                    \
                const int kd = z_ - 2 * i;                                   \
                if (kd >= 0 && kd <= 2) {                                    \
                    _Pragma("unroll")                                        \
                    for (int jj = 0; jj < 3; ++jj) {                         \
                        const int kh = y_ - 2 * jj;                          \
                        if (kh >= 0 && kh <= 2) {                            \
                            _Pragma("unroll")                                \
                            for (int k = 0; k < 3; ++k)                      \
                            _Pragma("unroll")                                \
                            for (int kw = 0; kw < 3; ++kw)                   \
                                p[i * 9 + jj * 3 + k] +=                     \
                                    row[2 * k + kw] * wr[kd * 9 + kh * 3 + kw]; \
                        }                                                    \
                    }                                                        \
                }                                                            \
            }                                                                \
        }

        if (rh == 0) {
            #pragma unroll
            for (int zy = 0; zy < 25; ++zy) C2_BODY(zy)
        } else {
            #pragma unroll
            for (int zy = 25; zy < 49; ++zy) C2_BODY(zy)
        }
#undef C2_BODY

        #pragma unroll
        for (int q = 0; q < 27; ++q) {            // 32-ci butterfly allreduce
            p[q] += __shfl_xor(p[q], 1);
            p[q] += __shfl_xor(p[q], 2);
            p[q] += __shfl_xor(p[q], 4);
            p[q] += __shfl_xor(p[q], 8);
            p[q] += __shfl_xor(p[q], 16);
        }
        float val = 0.f;
        #pragma unroll
        for (int q = 0; q < 27; ++q)              // compile-time reg index
            if (ci == q) val = p[q];
        if (ci < 27)
            s_part2[(co_l * 2 + rh) * 27 + ci] = val;
    }
    __syncthreads();
    // combine row-halves + BN + ReLU -> s_x2f[co*27+q]
    if (tid < 108) {
        const int co = tid / 27, q = tid % 27;
        float s = s_part2[(co * 2) * 27 + q] + s_part2[(co * 2 + 1) * 27 + q];
        s_x2f[tid] = fmaxf(s * sa2[co] + ss2[co], 0.f);
    }
    __syncthreads();

    // ---- conv3 PARTIAL (4 ci x 128 co3) -> part[b*16+g][128] ----
    // For fixed co3 the 4-ci w3 slice is CONTIGUOUS: 108 floats at
    // w3 + co3*1728 + g*108, matching s_x2f's layout. 32 groups x 4 co3.
    {
        const int gi = tid >> 4, j = tid & 15;
        #pragma unroll
        for (int cc = 0; cc < 4; ++cc) {
            const int co3 = gi * 4 + cc;
            const float* wrow = w3 + (size_t)co3 * 1728 + g * 108;
            float acc = 0.f;
            #pragma unroll
            for (int t = 0; t < 7; ++t) {
                const int idx = j + 16 * t;
                if (idx < 108)
                    acc += wrow[idx] * s_x2f[idx];
            }
            acc += __shfl_xor(acc, 1);
            acc += __shfl_xor(acc, 2);
            acc += __shfl_xor(acc, 4);
            acc += __shfl_xor(acc, 8);
            if (j == 0)
                __hip_atomic_store(&part[(size_t)(b * 16 + g) * 128 + co3], acc,
                                   __ATOMIC_RELAXED, __HIP_MEMORY_SCOPE_AGENT);
        }
    }
    __syncthreads();   // waitcnt vmcnt(0) before barrier: part stores accepted
    if (tid == 0)
        __hip_atomic_store(&flag1[b * 16 + g], MAGIC,
                           __ATOMIC_RELAXED, __HIP_MEMORY_SCOPE_AGENT);

    // ---- non-finisher blocks are done ----
    if (g != 0) return;

    // ---- finisher (g==0): poll 16 flags, gather, reduce, BN+ReLU, FC ----
    if (tid < 16) {
        while (__hip_atomic_load(&flag1[b * 16 + tid], __ATOMIC_RELAXED,
                                 __HIP_MEMORY_SCOPE_AGENT) != MAGIC) {
            __builtin_amdgcn_s_sleep(1);
        }
    }
    __syncthreads();
    #pragma unroll
    for (int it = 0; it < 4; ++it) {              // gather 2048 partials
        const int idx = it * 512 + tid;           // [gg = idx>>7][co3 = idx&127]
        s_p[idx] = __hip_atomic_load(
            &part[(size_t)(b * 16 + (idx >> 7)) * 128 + (idx & 127)],
            __ATOMIC_RELAXED, __HIP_MEMORY_SCOPE_AGENT);
    }
    __syncthreads();
    if (tid < 128) {                              // fixed-order 16-way sum
        const int co3 = tid;
        float s = 0.f;
        #pragma unroll
        for (int gg = 0; gg < 16; ++gg)
            s += s_p[gg * 128 + co3];
        float a = g3[co3] * rsqrtf(v3[co3] + BN_EPS);
        float sh = b3[co3] - m3[co3] * a;
        s_x3[co3] = fmaxf(s * a + sh, 0.f);
    }
    __syncthreads();
    {   // FC split-K: half = tid>>8 covers c in [half*64, half*64+64)
        const int half = tid >> 8, f = tid & 255;
        float acc = 0.f;
        #pragma unroll
        for (int c = 0; c < 64; ++c)              // wp reads coalesced per c
            acc += s_x3[half * 64 + c] * wp[(half * 64 + c) * 256 + f];
        s_fc[half * 256 + f] = acc;
    }
    __syncthreads();
    if (tid < 256)
        out[b * 256 + tid] = bp[tid] + s_fc[tid] + s_fc[256 + tid];
}

extern "C" void kernel_launch(void* const* d_in, const int* in_sizes, int n_in,
                              void* d_out, int out_size, void* d_ws, size_t ws_size,
                              hipStream_t stream) {
    const float* voxel = (const float*)d_in[0];
    const float* w1 = (const float*)d_in[1];
    const float* g1 = (const float*)d_in[2];
    const float* b1 = (const float*)d_in[3];
    const float* m1 = (const float*)d_in[4];
    const float* v1 = (const float*)d_in[5];
    const float* w2 = (const float*)d_in[6];
    const float* g2 = (const float*)d_in[7];
    const float* b2 = (const float*)d_in[8];
    const float* m2 = (const float*)d_in[9];
    const float* v2 = (const float*)d_in[10];
    const float* w3 = (const float*)d_in[11];
    const float* g3 = (const float*)d_in[12];
    const float* b3 = (const float*)d_in[13];
    const float* m3 = (const float*)d_in[14];
    const float* v3 = (const float*)d_in[15];
    const float* wp = (const float*)d_in[16];
    const float* bp = (const float*)d_in[17];
    float* out = (float*)d_out;

    char* ws = (char*)d_ws;
    float* part  = (float*)ws;                       // 16*16*128 f = 128 KB
    int*   flag1 = (int*)(ws + 131072);              // 256 ints

    backbone_onenode_kernel<<<256, 512, 0, stream>>>(
        voxel, w1, g1, b1, m1, v1, w2, g2, b2, m2, v2,
        w3, g3, b3, m3, v3, wp, bp, part, flag1, out);
}